// Round 6
// baseline (406.973 us; speedup 1.0000x reference)
//
#include <hip/hip_runtime.h>
#include <cstdint>
#include <math.h>

typedef __bf16 bf16;
typedef __bf16 bf16x8 __attribute__((ext_vector_type(8)));
typedef __bf16 bf16x4 __attribute__((ext_vector_type(4)));
typedef float f32x4 __attribute__((ext_vector_type(4)));
typedef float f32x16 __attribute__((ext_vector_type(16)));

#define T_SEQ 2048
#define HID   4096
#define NQH   32
#define NKVH  2
#define HD    128
#define NQKV  4608
#define ATT_SCALE 0.08838834764831845f

#define VMCNT(n) asm volatile("s_waitcnt vmcnt(" #n ")" ::: "memory")

__device__ __forceinline__ void load_lds16(const void* g, void* l) {
    auto gp = (const __attribute__((address_space(1))) unsigned int*)(uintptr_t)g;
    auto lp = (__attribute__((address_space(3))) unsigned int*)(unsigned int)(uintptr_t)l;
    __builtin_amdgcn_global_load_lds(gp, lp, 16, 0, 0);
}

__device__ __forceinline__ f32x4 mfma16(bf16x8 a, bf16x8 b, f32x4 c) {
    return __builtin_amdgcn_mfma_f32_16x16x32_bf16(a, b, c, 0, 0, 0);
}

// ---------------- generic fp32 -> bf16 (n divisible by 2048) ----------------
__global__ void cvt_f32_bf16_kernel(const float* __restrict__ x, bf16* __restrict__ y) {
    size_t i = ((size_t)blockIdx.x * 256 + threadIdx.x) * 8;
    float4 a = *(const float4*)(x + i);
    float4 b = *(const float4*)(x + i + 4);
    bf16x8 o;
    o[0] = (bf16)a.x; o[1] = (bf16)a.y; o[2] = (bf16)a.z; o[3] = (bf16)a.w;
    o[4] = (bf16)b.x; o[5] = (bf16)b.y; o[6] = (bf16)b.z; o[7] = (bf16)b.w;
    *(bf16x8*)(y + i) = o;
}

// ---------------- GEMM: C[M][N] = A[M][K](bf16) * B[N][K](bf16)^T (+bias) ----------------
// 128x128 tile, BK=64, 2 waves each owning a 128x64 output strip, 32x32x16 MFMA.
// Halves LDS-read bytes per FLOP vs the 4-wave 16x16 version (LDS-read was the
// binding pipe: 45us vs 31us MFMA).
template <int OUT_BF16, int HAS_BIAS>
__global__ __launch_bounds__(128) void gemm_bt(const bf16* __restrict__ A,
                                               const bf16* __restrict__ B,
                                               const float* __restrict__ bias,
                                               void* __restrict__ Cout,
                                               int M, int N, int K) {
    __shared__ __align__(16) char sA[16384];  // [128][64] bf16, 128B/row, swizzled
    __shared__ __align__(16) char sB[16384];
    const int tid = threadIdx.x;              // 0..127
    const int wid = tid >> 6, l = tid & 63;
    const int l32 = l & 31, lh = l >> 5;      // row-in-frag, k-half
    const int bm = blockIdx.x * 128, bn = blockIdx.y * 128;

    f32x16 acc[4][2] = {};

    for (int k0 = 0; k0 < K; k0 += 64) {
        __syncthreads();
#pragma unroll
        for (int c8 = 0; c8 < 8; ++c8) {   // A tile: 1024 chunks of 16B
            int ch = c8 * 128 + tid;
            int row = ch >> 3, cc = ch & 7;
            load_lds16(A + (size_t)(bm + row) * K + k0 + (cc ^ (row & 7)) * 8,
                       sA + c8 * 2048 + wid * 1024);
        }
#pragma unroll
        for (int c8 = 0; c8 < 8; ++c8) {   // B tile
            int ch = c8 * 128 + tid;
            int row = ch >> 3, cc = ch & 7;
            load_lds16(B + (size_t)(bn + row) * K + k0 + (cc ^ (row & 7)) * 8,
                       sB + c8 * 2048 + wid * 1024);
        }
        __syncthreads();
#pragma unroll
        for (int ks = 0; ks < 4; ++ks) {
            const int kcol = ks * 32 + lh * 16;   // byte offset of this lane's 8 k-elems
            bf16x8 af[4], bfr[2];
#pragma unroll
            for (int mi = 0; mi < 4; ++mi) {
                int row = mi * 32 + l32;
                af[mi] = *(const bf16x8*)(sA + row * 128 + (kcol ^ ((row & 7) << 4)));
            }
#pragma unroll
            for (int ni = 0; ni < 2; ++ni) {
                int row = wid * 64 + ni * 32 + l32;
                bfr[ni] = *(const bf16x8*)(sB + row * 128 + (kcol ^ ((row & 7) << 4)));
            }
#pragma unroll
            for (int mi = 0; mi < 4; ++mi)
#pragma unroll
                for (int ni = 0; ni < 2; ++ni)
                    acc[mi][ni] = __builtin_amdgcn_mfma_f32_32x32x16_bf16(af[mi], bfr[ni], acc[mi][ni], 0, 0, 0);
        }
    }

#pragma unroll
    for (int mi = 0; mi < 4; ++mi)
#pragma unroll
        for (int ni = 0; ni < 2; ++ni) {
            const int col = bn + wid * 64 + ni * 32 + l32;
            float bv = HAS_BIAS ? bias[col] : 0.0f;
#pragma unroll
            for (int reg = 0; reg < 16; ++reg) {
                const int row = bm + mi * 32 + (reg & 3) + 8 * (reg >> 2) + 4 * lh;
                float val = acc[mi][ni][reg] + bv;
                if (OUT_BF16)
                    ((bf16*)Cout)[(size_t)row * N + col] = (bf16)val;
                else
                    ((float*)Cout)[(size_t)row * N + col] = val;
            }
        }
}

// ---------------- RoPE on Q,K ----------------
__global__ void rope_qk_kernel(const bf16* __restrict__ qkv,
                               bf16* __restrict__ qheads, bf16* __restrict__ kheads) {
    const int t = blockIdx.x;
    const int g = blockIdx.y;
    const int sub = threadIdx.x >> 6;
    const int l = threadIdx.x & 63;
    const bf16* src;
    bf16* dst;
    if (g < 8) {
        int hh = g * 4 + sub;
        src = qkv + (size_t)t * NQKV + hh * HD;
        dst = qheads + ((size_t)hh * T_SEQ + t) * HD;
    } else {
        if (sub >= 2) return;
        src = qkv + (size_t)t * NQKV + HID + sub * HD;
        dst = kheads + ((size_t)sub * T_SEQ + t) * HD;
    }
    if (l < 32) {
        const int i = l;
        float x1 = (float)src[2 * i], x2 = (float)src[2 * i + 1];
        float fr = (float)t * exp2f((float)i * (-13.287712379549449f / 32.0f));
        float sn = sinf(fr), cs = cosf(fr);
        dst[2 * i] = (bf16)(x1 * cs - x2 * sn);
        dst[2 * i + 1] = (bf16)(x2 * cs + x1 * sn);
    } else {
        const int j = l - 32;
        dst[64 + 2 * j] = src[64 + 2 * j];
        dst[64 + 2 * j + 1] = src[64 + 2 * j + 1];
    }
}

// ---------------- V transpose: qkv[T][4608] -> vt[2][128][T] bf16 ----------------
__global__ void v_trans_kernel(const bf16* __restrict__ qkv, bf16* __restrict__ vt) {
    const int t0 = blockIdx.x * 64;
    const int kvh = blockIdx.y;
    const int tid = threadIdx.x;
#pragma unroll
    for (int it = 0; it < 4; ++it) {
        int ch = it * 256 + tid;
        int d = ch >> 3, tc = ch & 7;
        int t = t0 + tc * 8;
        const bf16* src = qkv + (size_t)t * NQKV + 4352 + kvh * HD + d;
        bf16x8 v;
#pragma unroll
        for (int i = 0; i < 8; ++i) v[i] = src[(size_t)i * NQKV];
        *(bf16x8*)(vt + ((size_t)kvh * HD + d) * T_SEQ + t) = v;
    }
}

// ---------------- Flash attention v4 (unchanged from round 5) ----------------
__global__ __launch_bounds__(256, 1) void attn_fwd_kernel(const bf16* __restrict__ qh,
                                                          const bf16* __restrict__ kh,
                                                          const bf16* __restrict__ vt,
                                                          bf16* __restrict__ attnb) {
    __shared__ __align__(16) char sK[2][16384];   // [64 t][128 d] bf16, 256B/row, swizzled
    __shared__ __align__(16) char sV[16384];      // [128 d][64 t] bf16, 128B/row, swizzled
    __shared__ __align__(16) char sP[4][4096];    // per-wave [32 q][64 k] bf16, swizzled
    const int tid = threadIdx.x;
    const int wid = tid >> 6, l = tid & 63, l4 = l >> 4, l16 = l & 15;
    const int b = blockIdx.x;
    const int qb = 15 - (b >> 5);     // LPT: heavy q-blocks dispatched first
    const int h = b & 31, kvh = h >> 4;
    const int qbase = qb * 128 + wid * 32;

    auto stageK = [&](int buf, int kt) {
#pragma unroll
        for (int c4 = 0; c4 < 4; ++c4) {
            int ch = c4 * 256 + tid;
            int row = ch >> 4, cc = ch & 15;
            load_lds16(kh + ((size_t)kvh * T_SEQ + kt * 64 + row) * HD + (cc ^ (row & 7)) * 8,
                       sK[buf] + c4 * 4096 + wid * 1024);
        }
    };
    auto stageV = [&](int kt) {
#pragma unroll
        for (int c4 = 0; c4 < 4; ++c4) {
            int ch = c4 * 256 + tid;
            int row = ch >> 3, cc = ch & 7;
            load_lds16(vt + ((size_t)kvh * HD + row) * T_SEQ + kt * 64 + (cc ^ (row & 7)) * 8,
                       sV + c4 * 4096 + wid * 1024);
        }
    };

    bf16x8 qf[2][4];
#pragma unroll
    for (int rg = 0; rg < 2; ++rg) {
        const bf16* qp = qh + ((size_t)h * T_SEQ + qbase + rg * 16 + l16) * HD + l4 * 8;
#pragma unroll
        for (int f = 0; f < 4; ++f) qf[rg][f] = *(const bf16x8*)(qp + f * 32);
    }
    VMCNT(0);
    stageK(0, 0);

    f32x4 o[2][8] = {};
    float mr[2][4], lr[2][4];
#pragma unroll
    for (int rg = 0; rg < 2; ++rg)
#pragma unroll
        for (int r = 0; r < 4; ++r) { mr[rg][r] = -INFINITY; lr[rg][r] = 0.f; }

    const int nt = 2 * qb + 2;
    int cur = 0;
    for (int kt = 0; kt < nt; ++kt) {
        const bool havenext = (kt + 1 < nt);
        __builtin_amdgcn_s_barrier();
        __builtin_amdgcn_sched_barrier(0);
        stageV(kt);
        if (havenext) stageK(cur ^ 1, kt + 1);
        if (havenext) { VMCNT(16); } else { VMCNT(8); }
        __builtin_amdgcn_s_barrier();
        __builtin_amdgcn_sched_barrier(0);

        const bool active = (kt * 64) <= (qbase + 31);
        if (active) {
            f32x4 s[2][4] = {};
#pragma unroll
            for (int ct = 0; ct < 4; ++ct)
#pragma unroll
                for (int ks = 0; ks < 4; ++ks) {
                    int row = ct * 16 + l16;
                    bf16x8 kf = *(const bf16x8*)(sK[cur] + row * 256 + ((ks * 64 + l4 * 16) ^ ((row & 7) << 4)));
                    s[0][ct] = mfma16(qf[0][ks], kf, s[0][ct]);
                    s[1][ct] = mfma16(qf[1][ks], kf, s[1][ct]);
                }

            const bool diag = (kt * 64 + 63 > qbase);
            float sv[2][4][4];
#pragma unroll
            for (int rg = 0; rg < 2; ++rg)
#pragma unroll
                for (int ct = 0; ct < 4; ++ct)
#pragma unroll
                    for (int r = 0; r < 4; ++r) {
                        float x = s[rg][ct][r] * ATT_SCALE;
                        if (diag && (kt * 64 + ct * 16 + l16) > (qbase + rg * 16 + l4 * 4 + r)) x = -INFINITY;
                        sv[rg][ct][r] = x;
                    }

            float pmx[2][4];
            bool ok = true;
#pragma unroll
            for (int rg = 0; rg < 2; ++rg)
#pragma unroll
                for (int r = 0; r < 4; ++r) {
                    pmx[rg][r] = fmaxf(fmaxf(sv[rg][0][r], sv[rg][1][r]), fmaxf(sv[rg][2][r], sv[rg][3][r]));
                    ok = ok && (pmx[rg][r] <= mr[rg][r] + 8.0f);
                }
            if (!__all(ok)) {
#pragma unroll
                for (int rg = 0; rg < 2; ++rg)
#pragma unroll
                    for (int r = 0; r < 4; ++r) {
                        float mx = pmx[rg][r];
                        mx = fmaxf(mx, __shfl_xor(mx, 1));
                        mx = fmaxf(mx, __shfl_xor(mx, 2));
                        mx = fmaxf(mx, __shfl_xor(mx, 4));
                        mx = fmaxf(mx, __shfl_xor(mx, 8));
                        if (mx > mr[rg][r]) {
                            float al = __expf(mr[rg][r] - mx);
                            mr[rg][r] = mx;
                            lr[rg][r] *= al;
#pragma unroll
                            for (int n2 = 0; n2 < 8; ++n2) o[rg][n2][r] *= al;
                        }
                    }
            }
#pragma unroll
            for (int rg = 0; rg < 2; ++rg)
#pragma unroll
                for (int r = 0; r < 4; ++r) {
                    float ps = 0.f;
                    const int prow = rg * 16 + l4 * 4 + r;
#pragma unroll
                    for (int ct = 0; ct < 4; ++ct) {
                        float p = __expf(sv[rg][ct][r] - mr[rg][r]);
                        ps += p;
                        *(bf16*)(sP[wid] + prow * 128 + (((ct * 16 + l16) * 2) ^ ((prow & 7) << 4))) = (bf16)p;
                    }
                    lr[rg][r] += ps;
                }
        }

        if (havenext) { VMCNT(8); } else { VMCNT(0); }
        __builtin_amdgcn_s_barrier();
        __builtin_amdgcn_sched_barrier(0);

        if (active) {
#pragma unroll
            for (int ks = 0; ks < 2; ++ks) {
                bf16x8 pa0 = *(const bf16x8*)(sP[wid] + l16 * 128 + ((ks * 64 + l4 * 16) ^ ((l16 & 7) << 4)));
                bf16x8 pa1 = *(const bf16x8*)(sP[wid] + (16 + l16) * 128 + ((ks * 64 + l4 * 16) ^ ((l16 & 7) << 4)));
#pragma unroll
                for (int n2 = 0; n2 < 8; ++n2) {
                    int vrow = n2 * 16 + l16;
                    bf16x8 vf = *(const bf16x8*)(sV + vrow * 128 + ((ks * 64 + l4 * 16) ^ ((vrow & 7) << 4)));
                    o[0][n2] = mfma16(pa0, vf, o[0][n2]);
                    o[1][n2] = mfma16(pa1, vf, o[1][n2]);
                }
            }
        }
        cur ^= 1;
    }

    float inv[2][4];
#pragma unroll
    for (int rg = 0; rg < 2; ++rg)
#pragma unroll
        for (int r = 0; r < 4; ++r) {
            float s2 = lr[rg][r];
            s2 += __shfl_xor(s2, 1);
            s2 += __shfl_xor(s2, 2);
            s2 += __shfl_xor(s2, 4);
            s2 += __shfl_xor(s2, 8);
            inv[rg][r] = 1.0f / s2;
        }
#pragma unroll
    for (int rg = 0; rg < 2; ++rg)
#pragma unroll
        for (int n2 = 0; n2 < 8; ++n2)
#pragma unroll
            for (int r = 0; r < 4; ++r) {
                int row = qb * 128 + wid * 32 + rg * 16 + l4 * 4 + r;
                int col = h * HD + n2 * 16 + l16;
                attnb[(size_t)row * HID + col] = (bf16)(o[rg][n2][r] * inv[rg][r]);
            }
}

extern "C" void kernel_launch(void* const* d_in, const int* in_sizes, int n_in,
                              void* d_out, int out_size, void* d_ws, size_t ws_size,
                              hipStream_t stream) {
    const float* hs = (const float*)d_in[0];
    const float* wqkv = (const float*)d_in[2];
    const float* bqkv = (const float*)d_in[3];
    const float* wdense = (const float*)d_in[4];
    float* out = (float*)d_out;

    char* ws = (char*)d_ws;
    bf16* wqkvb   = (bf16*)(ws + 0);
    bf16* hb      = (bf16*)(ws + 37748736);
    bf16* qkvb    = (bf16*)(ws + 54525952);
    bf16* qhp     = (bf16*)(ws + 0);
    bf16* khp     = (bf16*)(ws + 16777216);
    bf16* vtp     = (bf16*)(ws + 17825792);
    bf16* wdenseb = (bf16*)(ws + 18874368);
    bf16* attnb   = (bf16*)(ws + 54525952);
    (void)in_sizes; (void)n_in; (void)out_size; (void)ws_size;

    cvt_f32_bf16_kernel<<<(T_SEQ * HID) / 2048, 256, 0, stream>>>(hs, hb);
    cvt_f32_bf16_kernel<<<(NQKV * HID) / 2048, 256, 0, stream>>>(wqkv, wqkvb);

    dim3 g1(T_SEQ / 128, NQKV / 128);
    gemm_bt<1, 1><<<g1, 128, 0, stream>>>(hb, wqkvb, bqkv, (void*)qkvb, T_SEQ, NQKV, HID);

    cvt_f32_bf16_kernel<<<(HID * HID) / 2048, 256, 0, stream>>>(wdense, wdenseb);

    rope_qk_kernel<<<dim3(T_SEQ, 9), 256, 0, stream>>>(qkvb, qhp, khp);
    v_trans_kernel<<<dim3(T_SEQ / 64, NKVH), 256, 0, stream>>>(qkvb, vtp);

    attn_fwd_kernel<<<512, 256, 0, stream>>>(qhp, khp, vtp, attnb);

    dim3 g2(T_SEQ / 128, HID / 128);
    gemm_bt<0, 0><<<g2, 128, 0, stream>>>(attnb, wdenseb, nullptr, (void*)out, T_SEQ, HID, HID);
}

// Round 7
// 339.720 us; speedup vs baseline: 1.1980x; 1.1980x over previous
//
#include <hip/hip_runtime.h>
#include <cstdint>
#include <math.h>

typedef __bf16 bf16;
typedef __bf16 bf16x8 __attribute__((ext_vector_type(8)));
typedef __bf16 bf16x4 __attribute__((ext_vector_type(4)));
typedef float f32x4 __attribute__((ext_vector_type(4)));

#define T_SEQ 2048
#define HID   4096
#define NQH   32
#define NKVH  2
#define HD    128
#define NQKV  4608
#define ATT_SCALE 0.08838834764831845f

#define VMCNT(n) asm volatile("s_waitcnt vmcnt(" #n ")" ::: "memory")

__device__ __forceinline__ void load_lds16(const void* g, void* l) {
    auto gp = (const __attribute__((address_space(1))) unsigned int*)(uintptr_t)g;
    auto lp = (__attribute__((address_space(3))) unsigned int*)(unsigned int)(uintptr_t)l;
    __builtin_amdgcn_global_load_lds(gp, lp, 16, 0, 0);
}

__device__ __forceinline__ f32x4 mfma16(bf16x8 a, bf16x8 b, f32x4 c) {
    return __builtin_amdgcn_mfma_f32_16x16x32_bf16(a, b, c, 0, 0, 0);
}

// ---------------- generic fp32 -> bf16 (n divisible by 2048) ----------------
__global__ void cvt_f32_bf16_kernel(const float* __restrict__ x, bf16* __restrict__ y) {
    size_t i = ((size_t)blockIdx.x * 256 + threadIdx.x) * 8;
    float4 a = *(const float4*)(x + i);
    float4 b = *(const float4*)(x + i + 4);
    bf16x8 o;
    o[0] = (bf16)a.x; o[1] = (bf16)a.y; o[2] = (bf16)a.z; o[3] = (bf16)a.w;
    o[4] = (bf16)b.x; o[5] = (bf16)b.y; o[6] = (bf16)b.z; o[7] = (bf16)b.w;
    *(bf16x8*)(y + i) = o;
}

// ---------------- GEMM: C[M][N] = A[M][K](bf16) * B[N][K](bf16)^T (+bias) ----------------
// Round-5 known-good: 128x128 tile, BK=64, 4 waves (2x2), 16x16x32 MFMA,
// XOR-swizzled LDS, both operands via global_load_lds w=16, 0 bank conflicts.
template <int OUT_BF16, int HAS_BIAS>
__global__ __launch_bounds__(256) void gemm_bt(const bf16* __restrict__ A,
                                               const bf16* __restrict__ B,
                                               const float* __restrict__ bias,
                                               void* __restrict__ Cout,
                                               int M, int N, int K) {
    __shared__ __align__(16) char sA[16384];  // [128][64] bf16, 128B/row, swizzled
    __shared__ __align__(16) char sB[16384];
    const int tid = threadIdx.x;
    const int wid = tid >> 6, l = tid & 63, l4 = l >> 4, l16 = l & 15;
    const int wm = wid >> 1, wn = wid & 1;
    const int bm = blockIdx.x * 128, bn = blockIdx.y * 128;

    f32x4 acc[4][4] = {};

    for (int k0 = 0; k0 < K; k0 += 64) {
        __syncthreads();
#pragma unroll
        for (int c4 = 0; c4 < 4; ++c4) {
            int ch = c4 * 256 + tid;
            int row = ch >> 3, cch = ch & 7;
            int scc = cch ^ (row & 7);
            load_lds16(A + (size_t)(bm + row) * K + k0 + scc * 8,
                       sA + c4 * 4096 + wid * 1024);
        }
#pragma unroll
        for (int c4 = 0; c4 < 4; ++c4) {
            int ch = c4 * 256 + tid;
            int row = ch >> 3, cch = ch & 7;
            int scc = cch ^ (row & 7);
            load_lds16(B + (size_t)(bn + row) * K + k0 + scc * 8,
                       sB + c4 * 4096 + wid * 1024);
        }
        __syncthreads();
#pragma unroll
        for (int ks = 0; ks < 2; ++ks) {
            bf16x8 af[4], bfr[4];
#pragma unroll
            for (int mi = 0; mi < 4; ++mi) {
                int row = wm * 64 + mi * 16 + l16;
                af[mi] = *(const bf16x8*)(sA + row * 128 + ((ks * 64 + l4 * 16) ^ ((row & 7) << 4)));
            }
#pragma unroll
            for (int ni = 0; ni < 4; ++ni) {
                int row = wn * 64 + ni * 16 + l16;
                bfr[ni] = *(const bf16x8*)(sB + row * 128 + ((ks * 64 + l4 * 16) ^ ((row & 7) << 4)));
            }
#pragma unroll
            for (int mi = 0; mi < 4; ++mi)
#pragma unroll
                for (int ni = 0; ni < 4; ++ni)
                    acc[mi][ni] = mfma16(af[mi], bfr[ni], acc[mi][ni]);
        }
    }

#pragma unroll
    for (int mi = 0; mi < 4; ++mi)
#pragma unroll
        for (int ni = 0; ni < 4; ++ni) {
            const int col = bn + wn * 64 + ni * 16 + l16;
            float bv = HAS_BIAS ? bias[col] : 0.0f;
#pragma unroll
            for (int r = 0; r < 4; ++r) {
                const int row = bm + wm * 64 + mi * 16 + l4 * 4 + r;
                float val = acc[mi][ni][r] + bv;
                if (OUT_BF16)
                    ((bf16*)Cout)[(size_t)row * N + col] = (bf16)val;
                else
                    ((float*)Cout)[(size_t)row * N + col] = val;
            }
        }
}

// ---------------- RoPE on Q,K ----------------
__global__ void rope_qk_kernel(const bf16* __restrict__ qkv,
                               bf16* __restrict__ qheads, bf16* __restrict__ kheads) {
    const int t = blockIdx.x;
    const int g = blockIdx.y;
    const int sub = threadIdx.x >> 6;
    const int l = threadIdx.x & 63;
    const bf16* src;
    bf16* dst;
    if (g < 8) {
        int hh = g * 4 + sub;
        src = qkv + (size_t)t * NQKV + hh * HD;
        dst = qheads + ((size_t)hh * T_SEQ + t) * HD;
    } else {
        if (sub >= 2) return;
        src = qkv + (size_t)t * NQKV + HID + sub * HD;
        dst = kheads + ((size_t)sub * T_SEQ + t) * HD;
    }
    if (l < 32) {
        const int i = l;
        float x1 = (float)src[2 * i], x2 = (float)src[2 * i + 1];
        float fr = (float)t * exp2f((float)i * (-13.287712379549449f / 32.0f));
        float sn = sinf(fr), cs = cosf(fr);
        dst[2 * i] = (bf16)(x1 * cs - x2 * sn);
        dst[2 * i + 1] = (bf16)(x2 * cs + x1 * sn);
    } else {
        const int j = l - 32;
        dst[64 + 2 * j] = src[64 + 2 * j];
        dst[64 + 2 * j + 1] = src[64 + 2 * j + 1];
    }
}

// ---------------- V transpose: qkv[T][4608] -> vt[2][128][T] bf16 ----------------
__global__ void v_trans_kernel(const bf16* __restrict__ qkv, bf16* __restrict__ vt) {
    const int t0 = blockIdx.x * 64;
    const int kvh = blockIdx.y;
    const int tid = threadIdx.x;
#pragma unroll
    for (int it = 0; it < 4; ++it) {
        int ch = it * 256 + tid;
        int d = ch >> 3, tc = ch & 7;
        int t = t0 + tc * 8;
        const bf16* src = qkv + (size_t)t * NQKV + 4352 + kvh * HD + d;
        bf16x8 v;
#pragma unroll
        for (int i = 0; i < 8; ++i) v[i] = src[(size_t)i * NQKV];
        *(bf16x8*)(vt + ((size_t)kvh * HD + d) * T_SEQ + t) = v;
    }
}

// ---------------- Flash attention v4 + T5 setprio ----------------
__global__ __launch_bounds__(256, 1) void attn_fwd_kernel(const bf16* __restrict__ qh,
                                                          const bf16* __restrict__ kh,
                                                          const bf16* __restrict__ vt,
                                                          bf16* __restrict__ attnb) {
    __shared__ __align__(16) char sK[2][16384];   // [64 t][128 d] bf16, 256B/row, swizzled
    __shared__ __align__(16) char sV[16384];      // [128 d][64 t] bf16, 128B/row, swizzled
    __shared__ __align__(16) char sP[4][4096];    // per-wave [32 q][64 k] bf16, swizzled
    const int tid = threadIdx.x;
    const int wid = tid >> 6, l = tid & 63, l4 = l >> 4, l16 = l & 15;
    const int b = blockIdx.x;
    const int qb = 15 - (b >> 5);     // LPT: heavy q-blocks dispatched first
    const int h = b & 31, kvh = h >> 4;
    const int qbase = qb * 128 + wid * 32;

    auto stageK = [&](int buf, int kt) {
#pragma unroll
        for (int c4 = 0; c4 < 4; ++c4) {
            int ch = c4 * 256 + tid;
            int row = ch >> 4, cc = ch & 15;
            load_lds16(kh + ((size_t)kvh * T_SEQ + kt * 64 + row) * HD + (cc ^ (row & 7)) * 8,
                       sK[buf] + c4 * 4096 + wid * 1024);
        }
    };
    auto stageV = [&](int kt) {
#pragma unroll
        for (int c4 = 0; c4 < 4; ++c4) {
            int ch = c4 * 256 + tid;
            int row = ch >> 3, cc = ch & 7;
            load_lds16(vt + ((size_t)kvh * HD + row) * T_SEQ + kt * 64 + (cc ^ (row & 7)) * 8,
                       sV + c4 * 4096 + wid * 1024);
        }
    };

    bf16x8 qf[2][4];
#pragma unroll
    for (int rg = 0; rg < 2; ++rg) {
        const bf16* qp = qh + ((size_t)h * T_SEQ + qbase + rg * 16 + l16) * HD + l4 * 8;
#pragma unroll
        for (int f = 0; f < 4; ++f) qf[rg][f] = *(const bf16x8*)(qp + f * 32);
    }
    VMCNT(0);
    stageK(0, 0);

    f32x4 o[2][8] = {};
    float mr[2][4], lr[2][4];
#pragma unroll
    for (int rg = 0; rg < 2; ++rg)
#pragma unroll
        for (int r = 0; r < 4; ++r) { mr[rg][r] = -INFINITY; lr[rg][r] = 0.f; }

    const int nt = 2 * qb + 2;
    int cur = 0;
    for (int kt = 0; kt < nt; ++kt) {
        const bool havenext = (kt + 1 < nt);
        __builtin_amdgcn_s_barrier();
        __builtin_amdgcn_sched_barrier(0);
        stageV(kt);
        if (havenext) stageK(cur ^ 1, kt + 1);
        if (havenext) { VMCNT(16); } else { VMCNT(8); }
        __builtin_amdgcn_s_barrier();
        __builtin_amdgcn_sched_barrier(0);

        const bool active = (kt * 64) <= (qbase + 31);
        if (active) {
            f32x4 s[2][4] = {};
            __builtin_amdgcn_s_setprio(1);
#pragma unroll
            for (int ct = 0; ct < 4; ++ct)
#pragma unroll
                for (int ks = 0; ks < 4; ++ks) {
                    int row = ct * 16 + l16;
                    bf16x8 kf = *(const bf16x8*)(sK[cur] + row * 256 + ((ks * 64 + l4 * 16) ^ ((row & 7) << 4)));
                    s[0][ct] = mfma16(qf[0][ks], kf, s[0][ct]);
                    s[1][ct] = mfma16(qf[1][ks], kf, s[1][ct]);
                }
            __builtin_amdgcn_s_setprio(0);

            const bool diag = (kt * 64 + 63 > qbase);
            float sv[2][4][4];
#pragma unroll
            for (int rg = 0; rg < 2; ++rg)
#pragma unroll
                for (int ct = 0; ct < 4; ++ct)
#pragma unroll
                    for (int r = 0; r < 4; ++r) {
                        float x = s[rg][ct][r] * ATT_SCALE;
                        if (diag && (kt * 64 + ct * 16 + l16) > (qbase + rg * 16 + l4 * 4 + r)) x = -INFINITY;
                        sv[rg][ct][r] = x;
                    }

            float pmx[2][4];
            bool ok = true;
#pragma unroll
            for (int rg = 0; rg < 2; ++rg)
#pragma unroll
                for (int r = 0; r < 4; ++r) {
                    pmx[rg][r] = fmaxf(fmaxf(sv[rg][0][r], sv[rg][1][r]), fmaxf(sv[rg][2][r], sv[rg][3][r]));
                    ok = ok && (pmx[rg][r] <= mr[rg][r] + 8.0f);
                }
            if (!__all(ok)) {
#pragma unroll
                for (int rg = 0; rg < 2; ++rg)
#pragma unroll
                    for (int r = 0; r < 4; ++r) {
                        float mx = pmx[rg][r];
                        mx = fmaxf(mx, __shfl_xor(mx, 1));
                        mx = fmaxf(mx, __shfl_xor(mx, 2));
                        mx = fmaxf(mx, __shfl_xor(mx, 4));
                        mx = fmaxf(mx, __shfl_xor(mx, 8));
                        if (mx > mr[rg][r]) {
                            float al = __expf(mr[rg][r] - mx);
                            mr[rg][r] = mx;
                            lr[rg][r] *= al;
#pragma unroll
                            for (int n2 = 0; n2 < 8; ++n2) o[rg][n2][r] *= al;
                        }
                    }
            }
#pragma unroll
            for (int rg = 0; rg < 2; ++rg)
#pragma unroll
                for (int r = 0; r < 4; ++r) {
                    float ps = 0.f;
                    const int prow = rg * 16 + l4 * 4 + r;
#pragma unroll
                    for (int ct = 0; ct < 4; ++ct) {
                        float p = __expf(sv[rg][ct][r] - mr[rg][r]);
                        ps += p;
                        *(bf16*)(sP[wid] + prow * 128 + (((ct * 16 + l16) * 2) ^ ((prow & 7) << 4))) = (bf16)p;
                    }
                    lr[rg][r] += ps;
                }
        }

        if (havenext) { VMCNT(8); } else { VMCNT(0); }
        __builtin_amdgcn_s_barrier();
        __builtin_amdgcn_sched_barrier(0);

        if (active) {
#pragma unroll
            for (int ks = 0; ks < 2; ++ks) {
                bf16x8 pa0 = *(const bf16x8*)(sP[wid] + l16 * 128 + ((ks * 64 + l4 * 16) ^ ((l16 & 7) << 4)));
                bf16x8 pa1 = *(const bf16x8*)(sP[wid] + (16 + l16) * 128 + ((ks * 64 + l4 * 16) ^ ((l16 & 7) << 4)));
                __builtin_amdgcn_s_setprio(1);
#pragma unroll
                for (int n2 = 0; n2 < 8; ++n2) {
                    int vrow = n2 * 16 + l16;
                    bf16x8 vf = *(const bf16x8*)(sV + vrow * 128 + ((ks * 64 + l4 * 16) ^ ((vrow & 7) << 4)));
                    o[0][n2] = mfma16(pa0, vf, o[0][n2]);
                    o[1][n2] = mfma16(pa1, vf, o[1][n2]);
                }
                __builtin_amdgcn_s_setprio(0);
            }
        }
        cur ^= 1;
    }

    float inv[2][4];
#pragma unroll
    for (int rg = 0; rg < 2; ++rg)
#pragma unroll
        for (int r = 0; r < 4; ++r) {
            float s2 = lr[rg][r];
            s2 += __shfl_xor(s2, 1);
            s2 += __shfl_xor(s2, 2);
            s2 += __shfl_xor(s2, 4);
            s2 += __shfl_xor(s2, 8);
            inv[rg][r] = 1.0f / s2;
        }
#pragma unroll
    for (int rg = 0; rg < 2; ++rg)
#pragma unroll
        for (int n2 = 0; n2 < 8; ++n2)
#pragma unroll
            for (int r = 0; r < 4; ++r) {
                int row = qb * 128 + wid * 32 + rg * 16 + l4 * 4 + r;
                int col = h * HD + n2 * 16 + l16;
                attnb[(size_t)row * HID + col] = (bf16)(o[rg][n2][r] * inv[rg][r]);
            }
}

extern "C" void kernel_launch(void* const* d_in, const int* in_sizes, int n_in,
                              void* d_out, int out_size, void* d_ws, size_t ws_size,
                              hipStream_t stream) {
    const float* hs = (const float*)d_in[0];
    const float* wqkv = (const float*)d_in[2];
    const float* bqkv = (const float*)d_in[3];
    const float* wdense = (const float*)d_in[4];
    float* out = (float*)d_out;

    char* ws = (char*)d_ws;
    bf16* wqkvb   = (bf16*)(ws + 0);
    bf16* hb      = (bf16*)(ws + 37748736);
    bf16* qkvb    = (bf16*)(ws + 54525952);
    bf16* qhp     = (bf16*)(ws + 0);
    bf16* khp     = (bf16*)(ws + 16777216);
    bf16* vtp     = (bf16*)(ws + 17825792);
    bf16* wdenseb = (bf16*)(ws + 18874368);
    bf16* attnb   = (bf16*)(ws + 54525952);
    (void)in_sizes; (void)n_in; (void)out_size; (void)ws_size;

    cvt_f32_bf16_kernel<<<(T_SEQ * HID) / 2048, 256, 0, stream>>>(hs, hb);
    cvt_f32_bf16_kernel<<<(NQKV * HID) / 2048, 256, 0, stream>>>(wqkv, wqkvb);

    dim3 g1(T_SEQ / 128, NQKV / 128);
    gemm_bt<1, 1><<<g1, 256, 0, stream>>>(hb, wqkvb, bqkv, (void*)qkvb, T_SEQ, NQKV, HID);

    cvt_f32_bf16_kernel<<<(HID * HID) / 2048, 256, 0, stream>>>(wdense, wdenseb);

    rope_qk_kernel<<<dim3(T_SEQ, 9), 256, 0, stream>>>(qkvb, qhp, khp);
    v_trans_kernel<<<dim3(T_SEQ / 64, NKVH), 256, 0, stream>>>(qkvb, vtp);

    attn_fwd_kernel<<<512, 256, 0, stream>>>(qhp, khp, vtp, attnb);

    dim3 g2(T_SEQ / 128, HID / 128);
    gemm_bt<0, 0><<<g2, 256, 0, stream>>>(attnb, wdenseb, nullptr, (void*)out, T_SEQ, HID, HID);
}

// Round 8
// 326.370 us; speedup vs baseline: 1.2470x; 1.0409x over previous
//
#include <hip/hip_runtime.h>
#include <cstdint>
#include <math.h>

typedef __bf16 bf16;
typedef __bf16 bf16x8 __attribute__((ext_vector_type(8)));
typedef __bf16 bf16x4 __attribute__((ext_vector_type(4)));
typedef float f32x4 __attribute__((ext_vector_type(4)));

#define T_SEQ 2048
#define HID   4096
#define NQH   32
#define NKVH  2
#define HD    128
#define NQKV  4608
#define ATT_SCALE 0.08838834764831845f

#define VMCNT(n) asm volatile("s_waitcnt vmcnt(" #n ")" ::: "memory")

__device__ __forceinline__ void load_lds16(const void* g, void* l) {
    auto gp = (const __attribute__((address_space(1))) unsigned int*)(uintptr_t)g;
    auto lp = (__attribute__((address_space(3))) unsigned int*)(unsigned int)(uintptr_t)l;
    __builtin_amdgcn_global_load_lds(gp, lp, 16, 0, 0);
}

__device__ __forceinline__ f32x4 mfma16(bf16x8 a, bf16x8 b, f32x4 c) {
    return __builtin_amdgcn_mfma_f32_16x16x32_bf16(a, b, c, 0, 0, 0);
}

__device__ __forceinline__ bf16x8 cvt8(const float* s) {
    float4 a = *(const float4*)(s);
    float4 b = *(const float4*)(s + 4);
    bf16x8 o;
    o[0] = (bf16)a.x; o[1] = (bf16)a.y; o[2] = (bf16)a.z; o[3] = (bf16)a.w;
    o[4] = (bf16)b.x; o[5] = (bf16)b.y; o[6] = (bf16)b.z; o[7] = (bf16)b.w;
    return o;
}

// ---------------- fp32 -> bf16, two sources fused, grid-stride ----------------
__global__ void cvt2_kernel(const float* __restrict__ s0, bf16* __restrict__ d0, long n0,
                            const float* __restrict__ s1, bf16* __restrict__ d1, long n1) {
    const long nv = (n0 + n1) >> 3;
    for (long v = (long)blockIdx.x * 256 + threadIdx.x; v < nv; v += (long)gridDim.x * 256) {
        long i = v << 3;
        if (i < n0) *(bf16x8*)(d0 + i) = cvt8(s0 + i);
        else        *(bf16x8*)(d1 + (i - n0)) = cvt8(s1 + (i - n0));
    }
}

__global__ void cvt_f32_bf16_kernel(const float* __restrict__ x, bf16* __restrict__ y) {
    size_t i = ((size_t)blockIdx.x * 256 + threadIdx.x) * 8;
    *(bf16x8*)(y + i) = cvt8(x + i);
}

// ---------------- GEMM: C[M][N] = A[M][K](bf16) * B[N][K](bf16)^T (+bias) ----------------
// 128x128 tile, BK=64, 4 waves (2x2), 16x16x32 MFMA, XOR-swizzled LDS.
// Double-buffered with counted vmcnt: tile t+1's 8 global_load_lds stay in
// flight across tile t's compute; vmcnt(8) (never 0) drains only tile t.
template <int OUT_BF16, int HAS_BIAS>
__global__ __launch_bounds__(256) void gemm_bt(const bf16* __restrict__ A,
                                               const bf16* __restrict__ B,
                                               const float* __restrict__ bias,
                                               void* __restrict__ Cout,
                                               int M, int N, int K) {
    __shared__ __align__(16) char sA[2][16384];  // [128][64] bf16, 128B/row, swizzled
    __shared__ __align__(16) char sB[2][16384];
    const int tid = threadIdx.x;
    const int wid = tid >> 6, l = tid & 63, l4 = l >> 4, l16 = l & 15;
    const int wm = wid >> 1, wn = wid & 1;
    const int bm = blockIdx.x * 128, bn = blockIdx.y * 128;

    f32x4 acc[4][4] = {};

    auto stage = [&](int buf, int k0) {
#pragma unroll
        for (int c4 = 0; c4 < 4; ++c4) {
            int ch = c4 * 256 + tid;
            int row = ch >> 3, cch = ch & 7;
            int scc = cch ^ (row & 7);
            load_lds16(A + (size_t)(bm + row) * K + k0 + scc * 8,
                       sA[buf] + c4 * 4096 + wid * 1024);
        }
#pragma unroll
        for (int c4 = 0; c4 < 4; ++c4) {
            int ch = c4 * 256 + tid;
            int row = ch >> 3, cch = ch & 7;
            int scc = cch ^ (row & 7);
            load_lds16(B + (size_t)(bn + row) * K + k0 + scc * 8,
                       sB[buf] + c4 * 4096 + wid * 1024);
        }
    };

    stage(0, 0);
    const int NT = K >> 6;
    int cur = 0;
    for (int t = 0; t < NT; ++t) {
        __builtin_amdgcn_s_barrier();          // WAR: all waves done reading buf[cur^1]
        __builtin_amdgcn_sched_barrier(0);
        if (t + 1 < NT) {
            stage(cur ^ 1, (t + 1) * 64);      // issue next tile, stays in flight
            VMCNT(8);                          // drain tile t only
        } else {
            VMCNT(0);
        }
        __builtin_amdgcn_s_barrier();          // RAW: buf[cur] fully written
        __builtin_amdgcn_sched_barrier(0);

        const char* pA = sA[cur];
        const char* pB = sB[cur];
#pragma unroll
        for (int ks = 0; ks < 2; ++ks) {
            bf16x8 af[4], bfr[4];
#pragma unroll
            for (int mi = 0; mi < 4; ++mi) {
                int row = wm * 64 + mi * 16 + l16;
                af[mi] = *(const bf16x8*)(pA + row * 128 + ((ks * 64 + l4 * 16) ^ ((row & 7) << 4)));
            }
#pragma unroll
            for (int ni = 0; ni < 4; ++ni) {
                int row = wn * 64 + ni * 16 + l16;
                bfr[ni] = *(const bf16x8*)(pB + row * 128 + ((ks * 64 + l4 * 16) ^ ((row & 7) << 4)));
            }
#pragma unroll
            for (int mi = 0; mi < 4; ++mi)
#pragma unroll
                for (int ni = 0; ni < 4; ++ni)
                    acc[mi][ni] = mfma16(af[mi], bfr[ni], acc[mi][ni]);
        }
        cur ^= 1;
    }

#pragma unroll
    for (int mi = 0; mi < 4; ++mi)
#pragma unroll
        for (int ni = 0; ni < 4; ++ni) {
            const int col = bn + wn * 64 + ni * 16 + l16;
            float bv = HAS_BIAS ? bias[col] : 0.0f;
#pragma unroll
            for (int r = 0; r < 4; ++r) {
                const int row = bm + wm * 64 + mi * 16 + l4 * 4 + r;
                float val = acc[mi][ni][r] + bv;
                if (OUT_BF16)
                    ((bf16*)Cout)[(size_t)row * N + col] = (bf16)val;
                else
                    ((float*)Cout)[(size_t)row * N + col] = val;
            }
        }
}

// ---------------- RoPE on Q,K ----------------
__global__ void rope_qk_kernel(const bf16* __restrict__ qkv,
                               bf16* __restrict__ qheads, bf16* __restrict__ kheads) {
    const int t = blockIdx.x;
    const int g = blockIdx.y;
    const int sub = threadIdx.x >> 6;
    const int l = threadIdx.x & 63;
    const bf16* src;
    bf16* dst;
    if (g < 8) {
        int hh = g * 4 + sub;
        src = qkv + (size_t)t * NQKV + hh * HD;
        dst = qheads + ((size_t)hh * T_SEQ + t) * HD;
    } else {
        if (sub >= 2) return;
        src = qkv + (size_t)t * NQKV + HID + sub * HD;
        dst = kheads + ((size_t)sub * T_SEQ + t) * HD;
    }
    if (l < 32) {
        const int i = l;
        float x1 = (float)src[2 * i], x2 = (float)src[2 * i + 1];
        float fr = (float)t * exp2f((float)i * (-13.287712379549449f / 32.0f));
        float sn = sinf(fr), cs = cosf(fr);
        dst[2 * i] = (bf16)(x1 * cs - x2 * sn);
        dst[2 * i + 1] = (bf16)(x2 * cs + x1 * sn);
    } else {
        const int j = l - 32;
        dst[64 + 2 * j] = src[64 + 2 * j];
        dst[64 + 2 * j + 1] = src[64 + 2 * j + 1];
    }
}

// ---------------- V transpose: qkv[T][4608] -> vt[2][128][T] bf16 ----------------
__global__ void v_trans_kernel(const bf16* __restrict__ qkv, bf16* __restrict__ vt) {
    const int t0 = blockIdx.x * 64;
    const int kvh = blockIdx.y;
    const int tid = threadIdx.x;
#pragma unroll
    for (int it = 0; it < 4; ++it) {
        int ch = it * 256 + tid;
        int d = ch >> 3, tc = ch & 7;
        int t = t0 + tc * 8;
        const bf16* src = qkv + (size_t)t * NQKV + 4352 + kvh * HD + d;
        bf16x8 v;
#pragma unroll
        for (int i = 0; i < 8; ++i) v[i] = src[(size_t)i * NQKV];
        *(bf16x8*)(vt + ((size_t)kvh * HD + d) * T_SEQ + t) = v;
    }
}

// ---------------- Flash attention v4 + T5 setprio (round-7, validated) ----------------
__global__ __launch_bounds__(256, 1) void attn_fwd_kernel(const bf16* __restrict__ qh,
                                                          const bf16* __restrict__ kh,
                                                          const bf16* __restrict__ vt,
                                                          bf16* __restrict__ attnb) {
    __shared__ __align__(16) char sK[2][16384];   // [64 t][128 d] bf16, 256B/row, swizzled
    __shared__ __align__(16) char sV[16384];      // [128 d][64 t] bf16, 128B/row, swizzled
    __shared__ __align__(16) char sP[4][4096];    // per-wave [32 q][64 k] bf16, swizzled
    const int tid = threadIdx.x;
    const int wid = tid >> 6, l = tid & 63, l4 = l >> 4, l16 = l & 15;
    const int b = blockIdx.x;
    const int qb = 15 - (b >> 5);     // LPT: heavy q-blocks dispatched first
    const int h = b & 31, kvh = h >> 4;
    const int qbase = qb * 128 + wid * 32;

    auto stageK = [&](int buf, int kt) {
#pragma unroll
        for (int c4 = 0; c4 < 4; ++c4) {
            int ch = c4 * 256 + tid;
            int row = ch >> 4, cc = ch & 15;
            load_lds16(kh + ((size_t)kvh * T_SEQ + kt * 64 + row) * HD + (cc ^ (row & 7)) * 8,
                       sK[buf] + c4 * 4096 + wid * 1024);
        }
    };
    auto stageV = [&](int kt) {
#pragma unroll
        for (int c4 = 0; c4 < 4; ++c4) {
            int ch = c4 * 256 + tid;
            int row = ch >> 3, cc = ch & 7;
            load_lds16(vt + ((size_t)kvh * HD + row) * T_SEQ + kt * 64 + (cc ^ (row & 7)) * 8,
                       sV + c4 * 4096 + wid * 1024);
        }
    };

    bf16x8 qf[2][4];
#pragma unroll
    for (int rg = 0; rg < 2; ++rg) {
        const bf16* qp = qh + ((size_t)h * T_SEQ + qbase + rg * 16 + l16) * HD + l4 * 8;
#pragma unroll
        for (int f = 0; f < 4; ++f) qf[rg][f] = *(const bf16x8*)(qp + f * 32);
    }
    VMCNT(0);
    stageK(0, 0);

    f32x4 o[2][8] = {};
    float mr[2][4], lr[2][4];
#pragma unroll
    for (int rg = 0; rg < 2; ++rg)
#pragma unroll
        for (int r = 0; r < 4; ++r) { mr[rg][r] = -INFINITY; lr[rg][r] = 0.f; }

    const int nt = 2 * qb + 2;
    int cur = 0;
    for (int kt = 0; kt < nt; ++kt) {
        const bool havenext = (kt + 1 < nt);
        __builtin_amdgcn_s_barrier();
        __builtin_amdgcn_sched_barrier(0);
        stageV(kt);
        if (havenext) stageK(cur ^ 1, kt + 1);
        if (havenext) { VMCNT(16); } else { VMCNT(8); }
        __builtin_amdgcn_s_barrier();
        __builtin_amdgcn_sched_barrier(0);

        const bool active = (kt * 64) <= (qbase + 31);
        if (active) {
            f32x4 s[2][4] = {};
            __builtin_amdgcn_s_setprio(1);
#pragma unroll
            for (int ct = 0; ct < 4; ++ct)
#pragma unroll
                for (int ks = 0; ks < 4; ++ks) {
                    int row = ct * 16 + l16;
                    bf16x8 kf = *(const bf16x8*)(sK[cur] + row * 256 + ((ks * 64 + l4 * 16) ^ ((row & 7) << 4)));
                    s[0][ct] = mfma16(qf[0][ks], kf, s[0][ct]);
                    s[1][ct] = mfma16(qf[1][ks], kf, s[1][ct]);
                }
            __builtin_amdgcn_s_setprio(0);

            const bool diag = (kt * 64 + 63 > qbase);
            float sv[2][4][4];
#pragma unroll
            for (int rg = 0; rg < 2; ++rg)
#pragma unroll
                for (int ct = 0; ct < 4; ++ct)
#pragma unroll
                    for (int r = 0; r < 4; ++r) {
                        float x = s[rg][ct][r] * ATT_SCALE;
                        if (diag && (kt * 64 + ct * 16 + l16) > (qbase + rg * 16 + l4 * 4 + r)) x = -INFINITY;
                        sv[rg][ct][r] = x;
                    }

            float pmx[2][4];
            bool ok = true;
#pragma unroll
            for (int rg = 0; rg < 2; ++rg)
#pragma unroll
                for (int r = 0; r < 4; ++r) {
                    pmx[rg][r] = fmaxf(fmaxf(sv[rg][0][r], sv[rg][1][r]), fmaxf(sv[rg][2][r], sv[rg][3][r]));
                    ok = ok && (pmx[rg][r] <= mr[rg][r] + 8.0f);
                }
            if (!__all(ok)) {
#pragma unroll
                for (int rg = 0; rg < 2; ++rg)
#pragma unroll
                    for (int r = 0; r < 4; ++r) {
                        float mx = pmx[rg][r];
                        mx = fmaxf(mx, __shfl_xor(mx, 1));
                        mx = fmaxf(mx, __shfl_xor(mx, 2));
                        mx = fmaxf(mx, __shfl_xor(mx, 4));
                        mx = fmaxf(mx, __shfl_xor(mx, 8));
                        if (mx > mr[rg][r]) {
                            float al = __expf(mr[rg][r] - mx);
                            mr[rg][r] = mx;
                            lr[rg][r] *= al;
#pragma unroll
                            for (int n2 = 0; n2 < 8; ++n2) o[rg][n2][r] *= al;
                        }
                    }
            }
#pragma unroll
            for (int rg = 0; rg < 2; ++rg)
#pragma unroll
                for (int r = 0; r < 4; ++r) {
                    float ps = 0.f;
                    const int prow = rg * 16 + l4 * 4 + r;
#pragma unroll
                    for (int ct = 0; ct < 4; ++ct) {
                        float p = __expf(sv[rg][ct][r] - mr[rg][r]);
                        ps += p;
                        *(bf16*)(sP[wid] + prow * 128 + (((ct * 16 + l16) * 2) ^ ((prow & 7) << 4))) = (bf16)p;
                    }
                    lr[rg][r] += ps;
                }
        }

        if (havenext) { VMCNT(8); } else { VMCNT(0); }
        __builtin_amdgcn_s_barrier();
        __builtin_amdgcn_sched_barrier(0);

        if (active) {
#pragma unroll
            for (int ks = 0; ks < 2; ++ks) {
                bf16x8 pa0 = *(const bf16x8*)(sP[wid] + l16 * 128 + ((ks * 64 + l4 * 16) ^ ((l16 & 7) << 4)));
                bf16x8 pa1 = *(const bf16x8*)(sP[wid] + (16 + l16) * 128 + ((ks * 64 + l4 * 16) ^ ((l16 & 7) << 4)));
                __builtin_amdgcn_s_setprio(1);
#pragma unroll
                for (int n2 = 0; n2 < 8; ++n2) {
                    int vrow = n2 * 16 + l16;
                    bf16x8 vf = *(const bf16x8*)(sV + vrow * 128 + ((ks * 64 + l4 * 16) ^ ((vrow & 7) << 4)));
                    o[0][n2] = mfma16(pa0, vf, o[0][n2]);
                    o[1][n2] = mfma16(pa1, vf, o[1][n2]);
                }
                __builtin_amdgcn_s_setprio(0);
            }
        }
        cur ^= 1;
    }

    float inv[2][4];
#pragma unroll
    for (int rg = 0; rg < 2; ++rg)
#pragma unroll
        for (int r = 0; r < 4; ++r) {
            float s2 = lr[rg][r];
            s2 += __shfl_xor(s2, 1);
            s2 += __shfl_xor(s2, 2);
            s2 += __shfl_xor(s2, 4);
            s2 += __shfl_xor(s2, 8);
            inv[rg][r] = 1.0f / s2;
        }
#pragma unroll
    for (int rg = 0; rg < 2; ++rg)
#pragma unroll
        for (int n2 = 0; n2 < 8; ++n2)
#pragma unroll
            for (int r = 0; r < 4; ++r) {
                int row = qb * 128 + wid * 32 + rg * 16 + l4 * 4 + r;
                int col = h * HD + n2 * 16 + l16;
                attnb[(size_t)row * HID + col] = (bf16)(o[rg][n2][r] * inv[rg][r]);
            }
}

extern "C" void kernel_launch(void* const* d_in, const int* in_sizes, int n_in,
                              void* d_out, int out_size, void* d_ws, size_t ws_size,
                              hipStream_t stream) {
    const float* hs = (const float*)d_in[0];
    const float* wqkv = (const float*)d_in[2];
    const float* bqkv = (const float*)d_in[3];
    const float* wdense = (const float*)d_in[4];
    float* out = (float*)d_out;

    char* ws = (char*)d_ws;
    bf16* wqkvb   = (bf16*)(ws + 0);
    bf16* hb      = (bf16*)(ws + 37748736);
    bf16* qkvb    = (bf16*)(ws + 54525952);
    bf16* qhp     = (bf16*)(ws + 0);
    bf16* khp     = (bf16*)(ws + 16777216);
    bf16* vtp     = (bf16*)(ws + 17825792);
    bf16* wdenseb = (bf16*)(ws + 18874368);
    bf16* attnb   = (bf16*)(ws + 54525952);
    (void)in_sizes; (void)n_in; (void)out_size; (void)ws_size;

    cvt2_kernel<<<2048, 256, 0, stream>>>(hs, hb, (long)T_SEQ * HID,
                                          wqkv, wqkvb, (long)NQKV * HID);

    dim3 g1(T_SEQ / 128, NQKV / 128);
    gemm_bt<1, 1><<<g1, 256, 0, stream>>>(hb, wqkvb, bqkv, (void*)qkvb, T_SEQ, NQKV, HID);

    cvt_f32_bf16_kernel<<<(HID * HID) / 2048, 256, 0, stream>>>(wdense, wdenseb);

    rope_qk_kernel<<<dim3(T_SEQ, 9), 256, 0, stream>>>(qkvb, qhp, khp);
    v_trans_kernel<<<dim3(T_SEQ / 64, NKVH), 256, 0, stream>>>(qkvb, vtp);

    attn_fwd_kernel<<<512, 256, 0, stream>>>(qhp, khp, vtp, attnb);

    dim3 g2(T_SEQ / 128, HID / 128);
    gemm_bt<0, 0><<<g2, 256, 0, stream>>>(attnb, wdenseb, nullptr, (void*)out, T_SEQ, HID, HID);
}